// Round 2
// baseline (2151.174 us; speedup 1.0000x reference)
//
#include <hip/hip_runtime.h>
#include <cmath>

// Problem constants (from reference)
#define NN  5      // N_NODES
#define BB  4      // batch
#define CCH 256    // channels
#define HWD 1024   // H*W
#define THRESH_V 0.3f
#define EPS_V 1e-12f

// Tile config: block = 384 threads = 6 waves. Block computes a 64x64 output
// tile (64 channels x 64 hw) for node i, batch b. Wave w<5 computes stream
// A[i]@x[w]; wave 5 computes W2[i]@x[i]. 8x8 per-lane frag (optimal operand
// bytes/FMA for a 64-lane wave on a 64x64 tile).
//
// KC=16 (was 32): LDS = 29.2 KB -> with __launch_bounds__(384,6) we get
// 4 blocks = 24 waves/CU co-resident (was 1 block = 6 waves at 58 KB).
// Cross-block overlap hides stage latency + barriers; LDS-read pipe
// (~154 us floor) becomes the clean bottleneck.
#define CT 64      // channel rows per block
#define WT 64      // hw cols per block
#define KC 16      // k chunk
#define APAD 68    // padded LDS row stride (floats) for A/W2, 16B-aligned rows
#define SPAD 68    // Es row stride (floats) in epilogue

// smem layout (floats):
//   staging: Xs[5][16][64] @0 (5120) | As[16][68] @5120 (1088) | W2s @6208 (1088)
//   epilogue overlay: Es[6][16][68] @0 (6528)
#define XS_FLOATS (NN * KC * WT)          // 5120
#define AS_OFF    XS_FLOATS               // 5120
#define W2_OFF    (AS_OFF + KC * APAD)    // 6208
#define SMEM_FLOATS (W2_OFF + KC * APAD)  // 7296 floats = 29184 B

__global__ __launch_bounds__(384, 6)
void fub_main(const float* __restrict__ x, const float* __restrict__ wmat,
              const float* __restrict__ conv_w, const float* __restrict__ conv_b,
              float* __restrict__ out)
{
    __shared__ __align__(16) float smem[SMEM_FLOATS];
    float* Xs  = smem;            // [5][KC][WT]
    float* As  = smem + AS_OFF;   // [KC][APAD], As[k][r] = W1[i][c0+r][k]+W2[...]
    float* W2s = smem + W2_OFF;   // [KC][APAD]
    float* Es  = smem;            // [6][16][SPAD] overlay (epilogue only)

    const int tid  = threadIdx.x;
    const int wv   = tid >> 6;        // 0..5 : stream id
    const int lane = tid & 63;

    int bid = blockIdx.x;
    const int hwt = bid & 15; bid >>= 4;   // 16 hw tiles of 64
    const int b   = bid & 3;  bid >>= 2;   // 4 batches
    const int ct  = bid & 3;  bid >>= 2;   // 4 channel tiles of 64
    const int i   = bid;                   // 0..4

    const int c0  = ct * CT;
    const int hw0 = hwt * WT;

    const int lr = (lane >> 3) << 3;  // frag row base 0,8,...,56
    const int lc = (lane & 7)  << 3;  // frag col base 0,8,...,56

    // stream w<5 multiplies A by x[w]; stream 5 multiplies W2 by x[i]
    const int jx = (wv < 5) ? wv : i;
    const float* M  = (wv == 5) ? W2s : As;
    const float* Mb = M + lr;
    const float* Xb = Xs + jx * (KC * WT) + lc;

    float acc[8][8];
#pragma unroll
    for (int r = 0; r < 8; ++r)
#pragma unroll
        for (int c = 0; c < 8; ++c) acc[r][c] = 0.0f;

    for (int k0 = 0; k0 < CCH; k0 += KC) {
        // ---- stage: threads 0..319 load Xs (1280 float4), 320..383 load A/W2 ----
        if (tid < 320) {
#pragma unroll
            for (int it = 0; it < 4; ++it) {
                const int t   = tid + it * 320;       // 0..1279
                const int j   = t >> 8;               // 0..4
                const int rem = t & 255;
                const int kk  = rem >> 4;             // 0..15
                const int q4  = (rem & 15) << 2;      // 0..60
                const float4 v = *(const float4*)(
                    x + (size_t)((j * BB + b) * CCH + k0 + kk) * HWD + hw0 + q4);
                *(float4*)(Xs + j * (KC * WT) + kk * WT + q4) = v;
            }
        } else {
            const int u   = tid - 320;                // 0..63
            const int rb  = (u >> 2) << 2;            // row base 0,4,...,60
            const int kq4 = (u & 3) << 2;             // k quad base 0,4,8,12
            const float* base0 =
                conv_w + (size_t)(i * CCH + c0 + rb) * (2 * CCH) + k0 + kq4;
            float4 w1[4], w2[4];
#pragma unroll
            for (int rr = 0; rr < 4; ++rr) {
                w1[rr] = *(const float4*)(base0 + rr * (2 * CCH));
                w2[rr] = *(const float4*)(base0 + rr * (2 * CCH) + CCH);
            }
            // transpose in registers -> float4 LDS stores along rows
            *(float4*)(As + (kq4 + 0) * APAD + rb) = make_float4(
                w1[0].x + w2[0].x, w1[1].x + w2[1].x, w1[2].x + w2[2].x, w1[3].x + w2[3].x);
            *(float4*)(As + (kq4 + 1) * APAD + rb) = make_float4(
                w1[0].y + w2[0].y, w1[1].y + w2[1].y, w1[2].y + w2[2].y, w1[3].y + w2[3].y);
            *(float4*)(As + (kq4 + 2) * APAD + rb) = make_float4(
                w1[0].z + w2[0].z, w1[1].z + w2[1].z, w1[2].z + w2[2].z, w1[3].z + w2[3].z);
            *(float4*)(As + (kq4 + 3) * APAD + rb) = make_float4(
                w1[0].w + w2[0].w, w1[1].w + w2[1].w, w1[2].w + w2[2].w, w1[3].w + w2[3].w);
            *(float4*)(W2s + (kq4 + 0) * APAD + rb) = make_float4(w2[0].x, w2[1].x, w2[2].x, w2[3].x);
            *(float4*)(W2s + (kq4 + 1) * APAD + rb) = make_float4(w2[0].y, w2[1].y, w2[2].y, w2[3].y);
            *(float4*)(W2s + (kq4 + 2) * APAD + rb) = make_float4(w2[0].z, w2[1].z, w2[2].z, w2[3].z);
            *(float4*)(W2s + (kq4 + 3) * APAD + rb) = make_float4(w2[0].w, w2[1].w, w2[2].w, w2[3].w);
        }
        __syncthreads();

        // ---- compute: each wave does its stream's 64x64 tile, 8x8 frag/lane ----
#pragma unroll 4
        for (int kk = 0; kk < KC; ++kk) {
            const float4 a0  = *(const float4*)(Mb + kk * APAD);
            const float4 a1  = *(const float4*)(Mb + kk * APAD + 4);
            const float4 xv0 = *(const float4*)(Xb + kk * WT);
            const float4 xv1 = *(const float4*)(Xb + kk * WT + 4);
            const float ar[8] = {a0.x, a0.y, a0.z, a0.w, a1.x, a1.y, a1.z, a1.w};
            const float xc[8] = {xv0.x, xv0.y, xv0.z, xv0.w, xv1.x, xv1.y, xv1.z, xv1.w};
#pragma unroll
            for (int r = 0; r < 8; ++r)
#pragma unroll
                for (int c = 0; c < 8; ++c)
                    acc[r][c] = fmaf(ar[r], xc[c], acc[r][c]);
        }
        __syncthreads();
    }

    // ---- epilogue: 4 passes over 16-row bands; exchange streams via LDS ----
    const int rhme  = lr >> 4;        // which 16-row band this lane's frag is in
    const int rbase = lr & 15;        // 0 or 8

    float wrow[NN];
#pragma unroll
    for (int j = 0; j < NN; ++j) wrow[j] = wmat[i * NN + j];

#pragma unroll
    for (int rh = 0; rh < 4; ++rh) {
        if (rhme == rh) {
            float* Eb = Es + wv * (16 * SPAD) + lc;
#pragma unroll
            for (int r = 0; r < 8; ++r) {
                *(float4*)(Eb + (rbase + r) * SPAD) =
                    make_float4(acc[r][0], acc[r][1], acc[r][2], acc[r][3]);
                *(float4*)(Eb + (rbase + r) * SPAD + 4) =
                    make_float4(acc[r][4], acc[r][5], acc[r][6], acc[r][7]);
            }
        }
        __syncthreads();

        if (tid < 256) {
            const int row  = tid >> 4;           // 0..15
            const int colq = (tid & 15) << 2;    // 0..60
            const int c    = c0 + rh * 16 + row;
            const float bias = conv_b[i * CCH + c];

            const float4 T = *(const float4*)(Es + 5 * (16 * SPAD) + row * SPAD + colq);
            const float Tv[4] = {T.x, T.y, T.z, T.w};

            float num[4] = {0.f, 0.f, 0.f, 0.f};
            float sq [4] = {0.f, 0.f, 0.f, 0.f};
#pragma unroll
            for (int j = 0; j < NN; ++j) {
                const float4 s  = *(const float4*)(Es + j * (16 * SPAD) + row * SPAD + colq);
                const float4 xj = *(const float4*)(
                    x + (size_t)((j * BB + b) * CCH + c) * HWD + hw0 + colq);
                const float sv[4] = {s.x, s.y, s.z, s.w};
                const float xv[4] = {xj.x, xj.y, xj.z, xj.w};
#pragma unroll
                for (int cc = 0; cc < 4; ++cc) {
                    const float target = sv[cc] + Tv[cc] + bias;
                    const float dist   = xv[cc] - target;
                    const float z      = dist * wrow[j];
                    float e = 1.0f / (1.0f + expf(-z));
                    e = (e > THRESH_V) ? e : 0.0f;
                    sq[cc]  = fmaf(e, e, sq[cc]);
                    num[cc] = fmaf(e, xv[cc], num[cc]);
                }
            }
            float4 res;
            res.x = num[0] / fmaxf(sqrtf(sq[0]), EPS_V);
            res.y = num[1] / fmaxf(sqrtf(sq[1]), EPS_V);
            res.z = num[2] / fmaxf(sqrtf(sq[2]), EPS_V);
            res.w = num[3] / fmaxf(sqrtf(sq[3]), EPS_V);
            *(float4*)(out + (size_t)((i * BB + b) * CCH + c) * HWD + hw0 + colq) = res;
        }
        __syncthreads();
    }
}

extern "C" void kernel_launch(void* const* d_in, const int* in_sizes, int n_in,
                              void* d_out, int out_size, void* d_ws, size_t ws_size,
                              hipStream_t stream) {
    const float* x      = (const float*)d_in[0];
    const float* w      = (const float*)d_in[1];
    const float* conv_w = (const float*)d_in[2];
    const float* conv_b = (const float*)d_in[3];
    float* out = (float*)d_out;

    // grid: i(5) * ct(4) * b(4) * hwt(16) = 1280 blocks of 384 threads
    dim3 grid(1280);
    dim3 block(384);
    fub_main<<<grid, block, 0, stream>>>(x, w, conv_w, conv_b, out);
}

// Round 3
// 677.846 us; speedup vs baseline: 3.1735x; 3.1735x over previous
//
#include <hip/hip_runtime.h>
#include <cmath>

// Problem constants (from reference)
#define NN  5      // N_NODES
#define BB  4      // batch
#define CCH 256    // channels
#define HWD 1024   // H*W
#define THRESH_V 0.3f
#define EPS_V 1e-12f

// Strategy (R3): make the GEMM operand A wave-uniform so it rides the SMEM
// (scalar) pipe instead of the LDS pipe, which was the measured bottleneck
// (R1: ~153us LDS-instr floor vs 301us measured; R2: VGPR-cap spill, 7.2GB
// scratch traffic -> reverted cap).
//   - lane owns col = hw0+lane, all 64 rows: acc[64] VGPRs
//   - A[k][c0..c0+63] is wave-uniform -> s_load from a ws-transposed copy
//   - x[k][col] is one coalesced global_load_dword per k (L2/L3-resident)
//   - main loop: NO LDS, NO barriers. LDS only for the epilogue exchange.
// prep kernel builds At[i][k][c] = W1+W2 and W2t[i][k][c] into d_ws (2.6 MB).

#define CT 64      // channel rows per block
#define WT 64      // hw cols per block
#define SPAD 68    // Es row stride (floats) in epilogue

#define AT_FLOATS (NN * CCH * CCH)     // 327680
#define W2T_OFF   AT_FLOATS            // second table in ws
// Es[6][32][SPAD] epilogue exchange
#define SMEM_FLOATS (6 * 32 * SPAD)    // 13056 floats = 52224 B

// ---------------- prep: transpose conv_w into ws ----------------
// ws: At[i][k][c] = W1[i][c][k] + W2[i][c][k];  W2t[i][k][c] = W2[i][c][k]
__global__ void fub_prep(const float* __restrict__ conv_w, float* __restrict__ ws)
{
    const int t = blockIdx.x * 256 + threadIdx.x;   // 0 .. 5*256*64-1
    if (t >= NN * CCH * 64) return;
    const int c4 = (t & 63) << 2;        // c base 0..252
    const int k  = (t >> 6) & 255;       // 0..255
    const int i  = t >> 14;              // 0..4
    float s1[4], s2[4];
#pragma unroll
    for (int cc = 0; cc < 4; ++cc) {
        const float* p = conv_w + (size_t)(i * CCH + c4 + cc) * (2 * CCH) + k;
        const float w1 = p[0];
        const float w2 = p[CCH];
        s1[cc] = w1 + w2;
        s2[cc] = w2;
    }
    float* At  = ws + (size_t)(i * CCH + k) * CCH + c4;
    float* W2t = ws + W2T_OFF + (size_t)(i * CCH + k) * CCH + c4;
    *(float4*)At  = make_float4(s1[0], s1[1], s1[2], s1[3]);
    *(float4*)W2t = make_float4(s2[0], s2[1], s2[2], s2[3]);
}

// ---------------- main ----------------
__global__ __launch_bounds__(384, 4)
void fub_main(const float* __restrict__ x, const float* __restrict__ wmat,
              const float* __restrict__ ws, const float* __restrict__ conv_b,
              float* __restrict__ out)
{
    __shared__ __align__(16) float Es[SMEM_FLOATS];   // [6][32][SPAD]

    const int tid  = threadIdx.x;
    const int wv   = tid >> 6;        // 0..5 : stream id
    const int lane = tid & 63;
    // provably-uniform wave id so A loads scalarize to s_load
    const int wvu  = __builtin_amdgcn_readfirstlane(wv);

    int bid = blockIdx.x;
    const int i   = bid % 5;  bid /= 5;    // i,ct fastest: 20 consecutive
    const int ct  = bid & 3;  bid >>= 2;   // blocks share one x panel (L2)
    const int b   = bid & 3;  bid >>= 2;
    const int hwt = bid;                   // 0..15

    const int c0  = ct * CT;
    const int hw0 = hwt * WT;

    // stream w<5 multiplies A by x[w]; stream 5 multiplies W2 by x[i]
    const int jx = (wv < NN) ? wv : i;
    const float* Mb = ws + (size_t)((wvu == NN) ? W2T_OFF : 0)
                         + (size_t)i * CCH * CCH + c0;      // + k*CCH per step
    const float* xb = x + (size_t)((jx * BB + b) * CCH) * HWD + hw0 + lane;

    float acc[64];
#pragma unroll
    for (int r = 0; r < 64; ++r) acc[r] = 0.0f;

    // 4-deep x prefetch pipeline (one float per lane per k)
    float xf[4];
#pragma unroll
    for (int q = 0; q < 4; ++q) xf[q] = xb[(size_t)q * HWD];

    for (int k0 = 0; k0 < CCH; k0 += 4) {
        float xn[4];
        const int kn = (k0 + 4) & 255;     // last iter harmlessly reloads k=0..3
#pragma unroll
        for (int q = 0; q < 4; ++q) xn[q] = xb[(size_t)(kn + q) * HWD];
#pragma unroll
        for (int q = 0; q < 4; ++q) {
            const float xv = xf[q];
            const float4* Aq = (const float4*)(Mb + (size_t)(k0 + q) * CCH);
#pragma unroll
            for (int g = 0; g < 16; ++g) {
                const float4 a = Aq[g];    // wave-uniform -> SGPRs
                acc[4 * g + 0] = fmaf(a.x, xv, acc[4 * g + 0]);
                acc[4 * g + 1] = fmaf(a.y, xv, acc[4 * g + 1]);
                acc[4 * g + 2] = fmaf(a.z, xv, acc[4 * g + 2]);
                acc[4 * g + 3] = fmaf(a.w, xv, acc[4 * g + 3]);
            }
        }
#pragma unroll
        for (int q = 0; q < 4; ++q) xf[q] = xn[q];
    }

    // ---- epilogue: 2 passes over 32-row bands; exchange streams via LDS ----
    float wrow[NN];
#pragma unroll
    for (int j = 0; j < NN; ++j) wrow[j] = wmat[i * NN + j];

#pragma unroll
    for (int rh = 0; rh < 2; ++rh) {
        {
            float* Eb = Es + wv * (32 * SPAD) + lane;
#pragma unroll
            for (int rr = 0; rr < 32; ++rr)
                Eb[rr * SPAD] = acc[rh * 32 + rr];
        }
        __syncthreads();

        if (tid < 256) {
            const int row  = tid >> 3;           // 0..31
            const int col8 = (tid & 7) << 3;     // 0..56
            const int c    = c0 + rh * 32 + row;
            const float bias = conv_b[i * CCH + c];

#pragma unroll
            for (int h = 0; h < 2; ++h) {
                const int colq = col8 + 4 * h;

                const float4 T = *(const float4*)(Es + 5 * (32 * SPAD) + row * SPAD + colq);
                const float Tv[4] = {T.x, T.y, T.z, T.w};

                float num[4] = {0.f, 0.f, 0.f, 0.f};
                float sq [4] = {0.f, 0.f, 0.f, 0.f};
#pragma unroll
                for (int j = 0; j < NN; ++j) {
                    const float4 s  = *(const float4*)(Es + j * (32 * SPAD) + row * SPAD + colq);
                    const float4 xj = *(const float4*)(
                        x + (size_t)((j * BB + b) * CCH + c) * HWD + hw0 + colq);
                    const float sv[4] = {s.x, s.y, s.z, s.w};
                    const float xv[4] = {xj.x, xj.y, xj.z, xj.w};
#pragma unroll
                    for (int cc = 0; cc < 4; ++cc) {
                        const float target = sv[cc] + Tv[cc] + bias;
                        const float dist   = xv[cc] - target;
                        const float z      = dist * wrow[j];
                        float e = 1.0f / (1.0f + expf(-z));
                        e = (e > THRESH_V) ? e : 0.0f;
                        sq[cc]  = fmaf(e, e, sq[cc]);
                        num[cc] = fmaf(e, xv[cc], num[cc]);
                    }
                }
                float4 res;
                res.x = num[0] / fmaxf(sqrtf(sq[0]), EPS_V);
                res.y = num[1] / fmaxf(sqrtf(sq[1]), EPS_V);
                res.z = num[2] / fmaxf(sqrtf(sq[2]), EPS_V);
                res.w = num[3] / fmaxf(sqrtf(sq[3]), EPS_V);
                *(float4*)(out + (size_t)((i * BB + b) * CCH + c) * HWD + hw0 + colq) = res;
            }
        }
        __syncthreads();
    }
}

extern "C" void kernel_launch(void* const* d_in, const int* in_sizes, int n_in,
                              void* d_out, int out_size, void* d_ws, size_t ws_size,
                              hipStream_t stream) {
    const float* x      = (const float*)d_in[0];
    const float* w      = (const float*)d_in[1];
    const float* conv_w = (const float*)d_in[2];
    const float* conv_b = (const float*)d_in[3];
    float* out = (float*)d_out;
    float* ws  = (float*)d_ws;

    // prep: 5*256*64 = 81920 work items
    fub_prep<<<dim3(320), dim3(256), 0, stream>>>(conv_w, ws);

    // grid: hwt(16) * b(4) * ct(4) * i(5) = 1280 blocks of 384 threads
    fub_main<<<dim3(1280), dim3(384), 0, stream>>>(x, w, ws, conv_b, out);
}

// Round 5
// 346.747 us; speedup vs baseline: 6.2039x; 1.9549x over previous
//
#include <hip/hip_runtime.h>
#include <cmath>

// Problem constants (from reference)
#define NN  5      // N_NODES
#define BB  4      // batch
#define CCH 256    // channels
#define HWD 1024   // H*W
#define THRESH_V 0.3f
#define EPS_V 1e-12f

// R5: fp32 VALU GEMM (bf16/MFMA is correctness-dead: threshold flips).
// Dual-pipe operand feed:
//   - A (=W1+W2) and W2 pre-transposed to [i][k][c] in ws (R3-verified prep),
//     staged per 32-k chunk into 17.4 KB LDS, read as 2 ds_read_b128/kk.
//   - X read DIRECTLY from global per kk (2 dwordx4, 256B/wave, L1/L2-hit),
//     1-deep prefetch. No Xs staging, no LDS writes for X.
// LDS pipe demand halves vs R1 (~77us), VMEM ~50-100us, VALU 102us floor.
// 26 KB LDS + ~100 VGPR -> 3-4 blocks/CU (fixes R1's 1-block serialization).

#define CT 64      // channel rows per block
#define WT 64      // hw cols per block
#define KC 32      // k chunk
#define APAD 68    // As/W2s row stride (floats)
#define SPAD 68    // Es row stride (floats)

#define W2T_OFF (NN * CCH * CCH)       // second table in ws

#define AS_FLOATS   (KC * APAD)        // 2176
#define ES_FLOATS   (6 * 16 * SPAD)    // 6528 (epilogue overlay, 26112 B)
#define SMEM_FLOATS ES_FLOATS

// ---------------- prep: transpose conv_w into ws (verified R3) ----------------
// ws: At[i][k][c] = W1[i][c][k] + W2[i][c][k];  W2t[i][k][c] = W2[i][c][k]
__global__ void fub_prep(const float* __restrict__ conv_w, float* __restrict__ ws)
{
    const int t = blockIdx.x * 256 + threadIdx.x;   // 0 .. 5*256*64-1
    if (t >= NN * CCH * 64) return;
    const int c4 = (t & 63) << 2;        // c base 0..252
    const int k  = (t >> 6) & 255;       // 0..255
    const int i  = t >> 14;              // 0..4
    float s1[4], s2[4];
#pragma unroll
    for (int cc = 0; cc < 4; ++cc) {
        const float* p = conv_w + (size_t)(i * CCH + c4 + cc) * (2 * CCH) + k;
        const float w1 = p[0];
        const float w2 = p[CCH];
        s1[cc] = w1 + w2;
        s2[cc] = w2;
    }
    float* At  = ws + (size_t)(i * CCH + k) * CCH + c4;
    float* W2t = ws + W2T_OFF + (size_t)(i * CCH + k) * CCH + c4;
    *(float4*)At  = make_float4(s1[0], s1[1], s1[2], s1[3]);
    *(float4*)W2t = make_float4(s2[0], s2[1], s2[2], s2[3]);
}

// ---------------- main ----------------
__global__ __launch_bounds__(384, 4)
void fub_main(const float* __restrict__ x, const float* __restrict__ wmat,
              const float* __restrict__ ws, const float* __restrict__ conv_b,
              float* __restrict__ out)
{
    __shared__ __align__(16) float smem[SMEM_FLOATS];
    float* As  = smem;                 // [KC][APAD]
    float* W2s = smem + AS_FLOATS;     // [KC][APAD]
    float* Es  = smem;                 // [6][16][SPAD] overlay (epilogue only)

    const int tid  = threadIdx.x;
    const int wv   = tid >> 6;        // 0..5 : stream id
    const int lane = tid & 63;

    // XCD-chunked bijective swizzle (1280 % 8 == 0): the 20 blocks sharing one
    // x panel (b,hwt) land on one XCD's L2, A tables shared across all.
    const int wg  = blockIdx.x;
    int L = (wg & 7) * 160 + (wg >> 3);
    const int i   = L % 5;  L /= 5;
    const int ct  = L & 3;  L >>= 2;
    const int b   = L & 3;  L >>= 2;
    const int hwt = L;                 // 0..15

    const int c0  = ct * CT;
    const int hw0 = hwt * WT;

    const int lr = (lane >> 3) << 3;  // frag row base 0,8,...,56
    const int lc = (lane & 7)  << 3;  // frag col base 0,8,...,56

    // stream w<5: A_i @ x[w]; stream 5: W2_i @ x[i]
    const int jx = (wv < NN) ? wv : i;
    const float* Ms = (wv == 5) ? W2s : As;
    const float* Mb = Ms + lr;
    const float* xrow = x + (size_t)((jx * BB + b) * CCH) * HWD + hw0 + lc;

    float acc[8][8];
#pragma unroll
    for (int r = 0; r < 8; ++r)
#pragma unroll
        for (int c = 0; c < 8; ++c) acc[r][c] = 0.0f;

    // 1-deep X prefetch (8 floats/lane/kk, 256B distinct per wave -> L1/L2)
    float4 xn0 = *(const float4*)(xrow);
    float4 xn1 = *(const float4*)(xrow + 4);

    for (int k0 = 0; k0 < CCH; k0 += KC) {
        // ---- stage A/W2 chunk from ws (coalesced float4, no transpose) ----
#pragma unroll
        for (int it = 0; it < 3; ++it) {
            const int idx = tid + it * 384;        // 0..1151, need 0..1023
            if (idx < 1024) {
                const int tbl = idx >> 9;          // 0=A, 1=W2
                const int rem = idx & 511;
                const int kk  = rem >> 4;          // 0..31
                const int c4  = (rem & 15) << 2;   // 0..60
                const float4 v = *(const float4*)(
                    ws + (size_t)(tbl ? W2T_OFF : 0)
                       + (size_t)(i * CCH + k0 + kk) * CCH + c0 + c4);
                *(float4*)((tbl ? W2s : As) + kk * APAD + c4) = v;
            }
        }
        __syncthreads();

        // ---- compute: A from LDS, X from global (prefetched) ----
#pragma unroll 4
        for (int kk = 0; kk < KC; ++kk) {
            const float4 xc0 = xn0, xc1 = xn1;
            const int kn  = k0 + kk + 1;
            const int kcl = (kn < CCH) ? kn : (CCH - 1);   // last reload harmless
            xn0 = *(const float4*)(xrow + (size_t)kcl * HWD);
            xn1 = *(const float4*)(xrow + (size_t)kcl * HWD + 4);

            const float4 a0 = *(const float4*)(Mb + kk * APAD);
            const float4 a1 = *(const float4*)(Mb + kk * APAD + 4);
            const float ar[8] = {a0.x, a0.y, a0.z, a0.w, a1.x, a1.y, a1.z, a1.w};
            const float xv[8] = {xc0.x, xc0.y, xc0.z, xc0.w, xc1.x, xc1.y, xc1.z, xc1.w};
#pragma unroll
            for (int r = 0; r < 8; ++r)
#pragma unroll
                for (int c = 0; c < 8; ++c)
                    acc[r][c] = fmaf(ar[r], xv[c], acc[r][c]);
        }
        __syncthreads();
    }

    // ---- epilogue: 4 passes over 16-row bands; exchange streams via LDS ----
    const int rhme  = lr >> 4;        // which 16-row band this lane's frag is in
    const int rbase = lr & 15;        // 0 or 8

    float wrow[NN];
#pragma unroll
    for (int j = 0; j < NN; ++j) wrow[j] = wmat[i * NN + j];

#pragma unroll
    for (int rh = 0; rh < 4; ++rh) {
        if (rhme == rh) {
            float* Eb = Es + wv * (16 * SPAD) + lc;
#pragma unroll
            for (int r = 0; r < 8; ++r) {
                *(float4*)(Eb + (rbase + r) * SPAD) =
                    make_float4(acc[r][0], acc[r][1], acc[r][2], acc[r][3]);
                *(float4*)(Eb + (rbase + r) * SPAD + 4) =
                    make_float4(acc[r][4], acc[r][5], acc[r][6], acc[r][7]);
            }
        }
        __syncthreads();

        if (tid < 256) {
            const int row  = tid >> 4;           // 0..15
            const int colq = (tid & 15) << 2;    // 0..60
            const int c    = c0 + rh * 16 + row;
            const float bias = conv_b[i * CCH + c];

            const float4 T = *(const float4*)(Es + 5 * (16 * SPAD) + row * SPAD + colq);
            const float Tv[4] = {T.x, T.y, T.z, T.w};

            float num[4] = {0.f, 0.f, 0.f, 0.f};
            float sq [4] = {0.f, 0.f, 0.f, 0.f};
#pragma unroll
            for (int j = 0; j < NN; ++j) {
                const float4 s  = *(const float4*)(Es + j * (16 * SPAD) + row * SPAD + colq);
                const float4 xj = *(const float4*)(
                    x + (size_t)((j * BB + b) * CCH + c) * HWD + hw0 + colq);
                const float sv[4] = {s.x, s.y, s.z, s.w};
                const float xv[4] = {xj.x, xj.y, xj.z, xj.w};
#pragma unroll
                for (int cc = 0; cc < 4; ++cc) {
                    const float target = sv[cc] + Tv[cc] + bias;
                    const float dist   = xv[cc] - target;
                    const float z      = dist * wrow[j];
                    float e = 1.0f / (1.0f + expf(-z));
                    e = (e > THRESH_V) ? e : 0.0f;
                    sq[cc]  = fmaf(e, e, sq[cc]);
                    num[cc] = fmaf(e, xv[cc], num[cc]);
                }
            }
            float4 res;
            res.x = num[0] / fmaxf(sqrtf(sq[0]), EPS_V);
            res.y = num[1] / fmaxf(sqrtf(sq[1]), EPS_V);
            res.z = num[2] / fmaxf(sqrtf(sq[2]), EPS_V);
            res.w = num[3] / fmaxf(sqrtf(sq[3]), EPS_V);
            *(float4*)(out + (size_t)((i * BB + b) * CCH + c) * HWD + hw0 + colq) = res;
        }
        __syncthreads();
    }
}

extern "C" void kernel_launch(void* const* d_in, const int* in_sizes, int n_in,
                              void* d_out, int out_size, void* d_ws, size_t ws_size,
                              hipStream_t stream) {
    const float* x      = (const float*)d_in[0];
    const float* w      = (const float*)d_in[1];
    const float* conv_w = (const float*)d_in[2];
    const float* conv_b = (const float*)d_in[3];
    float* out = (float*)d_out;
    float* ws  = (float*)d_ws;   // needs 2*5*256*256*4 B = 2.62 MB

    // prep: 5*256*64 = 81920 work items
    fub_prep<<<dim3(320), dim3(256), 0, stream>>>(conv_w, ws);

    // grid: hwt(16) * b(4) * ct(4) * i(5) = 1280 blocks of 384 threads
    fub_main<<<dim3(1280), dim3(384), 0, stream>>>(x, w, ws, conv_b, out);
}

// Round 6
// 329.333 us; speedup vs baseline: 6.5319x; 1.0529x over previous
//
#include <hip/hip_runtime.h>
#include <cmath>

// Problem constants (from reference)
#define NN  5      // N_NODES
#define BB  4      // batch
#define CCH 256    // channels
#define HWD 1024   // H*W
#define THRESH_V 0.3f
#define EPS_V 1e-12f

// R6 = R5 structure (A via LDS, X direct from global w/ 1-deep prefetch,
// fp32 VALU GEMM) with the spill fixed: __launch_bounds__(384,3) (R1-proven
// no-spill register budget; R5's (384,4) made the compiler allocate only 64
// VGPRs and spill ~14 acc floats/thread -> 28MB scratch writes, VALU 52%).
// Also: prefetch clamp -> wrap (kn & 255), uniform AND instead of select.

#define CT 64      // channel rows per block
#define WT 64      // hw cols per block
#define KC 32      // k chunk
#define APAD 68    // As/W2s row stride (floats)
#define SPAD 68    // Es row stride (floats)

#define W2T_OFF (NN * CCH * CCH)       // second table in ws

#define AS_FLOATS   (KC * APAD)        // 2176
#define ES_FLOATS   (6 * 16 * SPAD)    // 6528 (epilogue overlay, 26112 B)
#define SMEM_FLOATS ES_FLOATS

// ---------------- prep: transpose conv_w into ws (verified R3) ----------------
// ws: At[i][k][c] = W1[i][c][k] + W2[i][c][k];  W2t[i][k][c] = W2[i][c][k]
__global__ void fub_prep(const float* __restrict__ conv_w, float* __restrict__ ws)
{
    const int t = blockIdx.x * 256 + threadIdx.x;   // 0 .. 5*256*64-1
    if (t >= NN * CCH * 64) return;
    const int c4 = (t & 63) << 2;        // c base 0..252
    const int k  = (t >> 6) & 255;       // 0..255
    const int i  = t >> 14;              // 0..4
    float s1[4], s2[4];
#pragma unroll
    for (int cc = 0; cc < 4; ++cc) {
        const float* p = conv_w + (size_t)(i * CCH + c4 + cc) * (2 * CCH) + k;
        const float w1 = p[0];
        const float w2 = p[CCH];
        s1[cc] = w1 + w2;
        s2[cc] = w2;
    }
    float* At  = ws + (size_t)(i * CCH + k) * CCH + c4;
    float* W2t = ws + W2T_OFF + (size_t)(i * CCH + k) * CCH + c4;
    *(float4*)At  = make_float4(s1[0], s1[1], s1[2], s1[3]);
    *(float4*)W2t = make_float4(s2[0], s2[1], s2[2], s2[3]);
}

// ---------------- main ----------------
__global__ __launch_bounds__(384, 3)
void fub_main(const float* __restrict__ x, const float* __restrict__ wmat,
              const float* __restrict__ ws, const float* __restrict__ conv_b,
              float* __restrict__ out)
{
    __shared__ __align__(16) float smem[SMEM_FLOATS];
    float* As  = smem;                 // [KC][APAD]
    float* W2s = smem + AS_FLOATS;     // [KC][APAD]
    float* Es  = smem;                 // [6][16][SPAD] overlay (epilogue only)

    const int tid  = threadIdx.x;
    const int wv   = tid >> 6;        // 0..5 : stream id
    const int lane = tid & 63;

    // XCD-chunked bijective swizzle (1280 % 8 == 0): the 20 blocks sharing one
    // x panel (b,hwt) land on one XCD's L2, A tables shared across all.
    const int wg  = blockIdx.x;
    int L = (wg & 7) * 160 + (wg >> 3);
    const int i   = L % 5;  L /= 5;
    const int ct  = L & 3;  L >>= 2;
    const int b   = L & 3;  L >>= 2;
    const int hwt = L;                 // 0..15

    const int c0  = ct * CT;
    const int hw0 = hwt * WT;

    const int lr = (lane >> 3) << 3;  // frag row base 0,8,...,56
    const int lc = (lane & 7)  << 3;  // frag col base 0,8,...,56

    // stream w<5: A_i @ x[w]; stream 5: W2_i @ x[i]
    const int jx = (wv < NN) ? wv : i;
    const float* Ms = (wv == 5) ? W2s : As;
    const float* Mb = Ms + lr;
    const float* xrow = x + (size_t)((jx * BB + b) * CCH) * HWD + hw0 + lc;

    float acc[8][8];
#pragma unroll
    for (int r = 0; r < 8; ++r)
#pragma unroll
        for (int c = 0; c < 8; ++c) acc[r][c] = 0.0f;

    // 1-deep X prefetch (8 floats/lane/kk, 256B distinct per wave -> L1/L2)
    float4 xn0 = *(const float4*)(xrow);
    float4 xn1 = *(const float4*)(xrow + 4);

    for (int k0 = 0; k0 < CCH; k0 += KC) {
        // ---- stage A/W2 chunk from ws (coalesced float4, no transpose) ----
#pragma unroll
        for (int it = 0; it < 3; ++it) {
            const int idx = tid + it * 384;        // 0..1151, need 0..1023
            if (idx < 1024) {
                const int tbl = idx >> 9;          // 0=A, 1=W2
                const int rem = idx & 511;
                const int kk  = rem >> 4;          // 0..31
                const int c4  = (rem & 15) << 2;   // 0..60
                const float4 v = *(const float4*)(
                    ws + (size_t)(tbl ? W2T_OFF : 0)
                       + (size_t)(i * CCH + k0 + kk) * CCH + c0 + c4);
                *(float4*)((tbl ? W2s : As) + kk * APAD + c4) = v;
            }
        }
        __syncthreads();

        // ---- compute: A from LDS, X from global (prefetched) ----
#pragma unroll 4
        for (int kk = 0; kk < KC; ++kk) {
            const float4 xc0 = xn0, xc1 = xn1;
            const int kn = (k0 + kk + 1) & 255;    // wrap: last reload reads k=0 (in-bounds, discarded)
            xn0 = *(const float4*)(xrow + (size_t)kn * HWD);
            xn1 = *(const float4*)(xrow + (size_t)kn * HWD + 4);

            const float4 a0 = *(const float4*)(Mb + kk * APAD);
            const float4 a1 = *(const float4*)(Mb + kk * APAD + 4);
            const float ar[8] = {a0.x, a0.y, a0.z, a0.w, a1.x, a1.y, a1.z, a1.w};
            const float xv[8] = {xc0.x, xc0.y, xc0.z, xc0.w, xc1.x, xc1.y, xc1.z, xc1.w};
#pragma unroll
            for (int r = 0; r < 8; ++r)
#pragma unroll
                for (int c = 0; c < 8; ++c)
                    acc[r][c] = fmaf(ar[r], xv[c], acc[r][c]);
        }
        __syncthreads();
    }

    // ---- epilogue: 4 passes over 16-row bands; exchange streams via LDS ----
    const int rhme  = lr >> 4;        // which 16-row band this lane's frag is in
    const int rbase = lr & 15;        // 0 or 8

    float wrow[NN];
#pragma unroll
    for (int j = 0; j < NN; ++j) wrow[j] = wmat[i * NN + j];

#pragma unroll
    for (int rh = 0; rh < 4; ++rh) {
        if (rhme == rh) {
            float* Eb = Es + wv * (16 * SPAD) + lc;
#pragma unroll
            for (int r = 0; r < 8; ++r) {
                *(float4*)(Eb + (rbase + r) * SPAD) =
                    make_float4(acc[r][0], acc[r][1], acc[r][2], acc[r][3]);
                *(float4*)(Eb + (rbase + r) * SPAD + 4) =
                    make_float4(acc[r][4], acc[r][5], acc[r][6], acc[r][7]);
            }
        }
        __syncthreads();

        if (tid < 256) {
            const int row  = tid >> 4;           // 0..15
            const int colq = (tid & 15) << 2;    // 0..60
            const int c    = c0 + rh * 16 + row;
            const float bias = conv_b[i * CCH + c];

            const float4 T = *(const float4*)(Es + 5 * (16 * SPAD) + row * SPAD + colq);
            const float Tv[4] = {T.x, T.y, T.z, T.w};

            float num[4] = {0.f, 0.f, 0.f, 0.f};
            float sq [4] = {0.f, 0.f, 0.f, 0.f};
#pragma unroll
            for (int j = 0; j < NN; ++j) {
                const float4 s  = *(const float4*)(Es + j * (16 * SPAD) + row * SPAD + colq);
                const float4 xj = *(const float4*)(
                    x + (size_t)((j * BB + b) * CCH + c) * HWD + hw0 + colq);
                const float sv[4] = {s.x, s.y, s.z, s.w};
                const float xv[4] = {xj.x, xj.y, xj.z, xj.w};
#pragma unroll
                for (int cc = 0; cc < 4; ++cc) {
                    const float target = sv[cc] + Tv[cc] + bias;
                    const float dist   = xv[cc] - target;
                    const float z      = dist * wrow[j];
                    float e = 1.0f / (1.0f + expf(-z));
                    e = (e > THRESH_V) ? e : 0.0f;
                    sq[cc]  = fmaf(e, e, sq[cc]);
                    num[cc] = fmaf(e, xv[cc], num[cc]);
                }
            }
            float4 res;
            res.x = num[0] / fmaxf(sqrtf(sq[0]), EPS_V);
            res.y = num[1] / fmaxf(sqrtf(sq[1]), EPS_V);
            res.z = num[2] / fmaxf(sqrtf(sq[2]), EPS_V);
            res.w = num[3] / fmaxf(sqrtf(sq[3]), EPS_V);
            *(float4*)(out + (size_t)((i * BB + b) * CCH + c) * HWD + hw0 + colq) = res;
        }
        __syncthreads();
    }
}

extern "C" void kernel_launch(void* const* d_in, const int* in_sizes, int n_in,
                              void* d_out, int out_size, void* d_ws, size_t ws_size,
                              hipStream_t stream) {
    const float* x      = (const float*)d_in[0];
    const float* w      = (const float*)d_in[1];
    const float* conv_w = (const float*)d_in[2];
    const float* conv_b = (const float*)d_in[3];
    float* out = (float*)d_out;
    float* ws  = (float*)d_ws;   // needs 2*5*256*256*4 B = 2.62 MB

    // prep: 5*256*64 = 81920 work items
    fub_prep<<<dim3(320), dim3(256), 0, stream>>>(conv_w, ws);

    // grid: hwt(16) * b(4) * ct(4) * i(5) = 1280 blocks of 384 threads
    fub_main<<<dim3(1280), dim3(384), 0, stream>>>(x, w, ws, conv_b, out);
}